// Round 1
// 101.452 us; speedup vs baseline: 1.0729x; 1.0729x over previous
//
#include <hip/hip_runtime.h>
#include <math.h>

// ---------------- problem constants ----------------
#define NS 3000          // 30*100 samples
#define NF 147           // 3*7*7 encoder feats
#define ND 512
#define NSIG 49          // 7x7 shift classes
#define NSAMP 4          // samples per k_H2s block (750 blocks -> ~3/CU)
#define NHBLK 750        // 3000 / 4
#define NBLK_VT 1029     // 7 sy * 147 f

// ---------------- ws layout (float offsets) ----------------
#define OFF_WT     0            // 6272 (7*224 float4: w0,w1,i0,i1)
#define OFF_FEATS  6272         // 160
#define OFF_T      236928       // T2[sig][g][f]: 49*49*147 = 352947 -> 589875
#define OFF_G      589952       // 7203
// end < 600240 floats = 2.4 MB

// weight of upsample(+reflect,+shift): output pixel p, shift sigma
__device__ __forceinline__ void wt_compute(int sigma, int p, int& i0c, int& i1c,
                                           float& w0, float& w1) {
  int k = p + sigma - 3;
  int r = k < 0 ? -k : (k > 223 ? 446 - k : k);    // np.pad 'reflect'
  float tc = (float)(2 * r - 31) * (1.0f / 64.0f); // (r+0.5)/32 - 0.5, exact
  float fl = floorf(tc);
  int i0 = (int)fl;
  float fr = tc - fl;
  i0c = min(max(i0, 0), 6);
  i1c = min(max(i0 + 1, 0), 6);
  w0 = 1.0f - fr;
  w1 = fr;
}

// Fused initV + T: one block per (sy, f). Loads the 32x32 x-tile into LDS,
// computes the 32x7 V column in LDS, reduces to T2[sig][g][f] directly.
// Extra blocks: 1029 -> WT table; 1030..1058 -> zero G.
// FP accumulation order identical to the old k_initV->k_T pipeline.
__global__ void __launch_bounds__(256) k_VT(const float* __restrict__ x,
                                            float* __restrict__ ws) {
  int b = blockIdx.x;
  int t = threadIdx.x;
  if (b >= NBLK_VT) {
    if (b == NBLK_VT) {
      float4* WT = (float4*)(ws + OFF_WT);
      for (int e = t; e < 7 * 224; e += 256) {
        int sigma = e / 224, p = e % 224;
        int i0c, i1c; float w0, w1;
        wt_compute(sigma, p, i0c, i1c, w0, w1);
        WT[e] = make_float4(w0, w1, __int_as_float(i0c), __int_as_float(i1c));
      }
    } else {
      int e = (b - NBLK_VT - 1) * 256 + t;
      if (e < 3 * 2401) ws[OFF_G + e] = 0.f;
    }
    return;
  }

  __shared__ float sX[32][33];       // padded: V-stage reads column-wise
  __shared__ float sV[32][8];        // [y0][gx]
  __shared__ float4 sWX[32];         // x-weights for this (sy, cx)
  __shared__ float4 sWY[7][32];      // y-weights [sx][y0] for this cy
  __shared__ float red[4];

  int f = b % NF;
  int sy = b / NF;
  int c = f / 49, rem = f % 49, cy = rem / 7, cx = rem % 7;

  // ---- load x tile (+ per-thread partial sum for feats) ----
  const float* xb = x + (c * 224 + cy * 32) * 224 + cx * 32;
  float psum = 0.f;
  for (int idx = t; idx < 1024; idx += 256) {
    int yy = idx >> 5, xx = idx & 31;
    float v = xb[yy * 224 + xx];
    sX[yy][xx] = v;
    psum += v;
  }

  // ---- weight tables ----
  if (t < 32) {
    int i0, i1; float w0, w1;
    wt_compute(sy, cx * 32 + t, i0, i1, w0, w1);
    sWX[t] = make_float4(w0, w1, __int_as_float(i0), __int_as_float(i1));
  } else if (t < 32 + 224) {
    int e = t - 32;
    int sx = e >> 5, y0 = e & 31;
    int i0, i1; float w0, w1;
    wt_compute(sx, cy * 32 + y0, i0, i1, w0, w1);
    sWY[sx][y0] = make_float4(w0, w1, __int_as_float(i0), __int_as_float(i1));
  }

  // ---- feats (h* input): only once per f, in the sy==0 blocks ----
  if (sy == 0) {
    float acc = psum;
    for (int off = 32; off; off >>= 1) acc += __shfl_down(acc, off);
    int wave = t >> 6, lane = t & 63;
    if (lane == 0) red[wave] = acc;
  }
  __syncthreads();
  if (sy == 0 && t == 0)
    ws[OFF_FEATS + f] = (red[0] + red[1] + red[2] + red[3]) * (1.0f / 1024.0f);

  // ---- V stage: sV[y0][gx] = sum_x0 wx * sX[y0][x0] ----
  if (t < 224) {
    int y0 = t / 7, gx = t % 7;
    float acc = 0.f;
    #pragma unroll
    for (int x0 = 0; x0 < 32; ++x0) {
      float4 wt = sWX[x0];
      int i0 = __float_as_int(wt.z), i1 = __float_as_int(wt.w);
      float w = (gx == i0 ? wt.x : 0.f) + (gx == i1 ? wt.y : 0.f);
      acc = fmaf(w, sX[y0][x0], acc);
    }
    sV[y0][gx] = acc;
  }
  __syncthreads();

  // ---- T2 stage: 343 outputs (sx, gy, gx) ----
  for (int e = t; e < 343; e += 256) {
    int sx = e / 49, r2 = e % 49, gy = r2 / 7, gx = r2 % 7;
    float acc = 0.f;
    #pragma unroll
    for (int y0 = 0; y0 < 32; ++y0) {
      float4 wt = sWY[sx][y0];
      int i0 = __float_as_int(wt.z), i1 = __float_as_int(wt.w);
      float w = (gy == i0 ? wt.x : 0.f) + (gy == i1 ? wt.y : 0.f);
      acc = fmaf(w, sV[y0][gx], acc);
    }
    ws[OFF_T + ((sx * 7 + sy) * 49 + gy * 7 + gx) * NF + f] = acc * (1.0f / 1024.0f);
  }
}

// fused: F = T2[sig]@g (LDS), h* col + H = F@Wenc one pass, s_i in LDS,
// then per-sample coalesced atomic flush into global G (k-fastest lanes)
__global__ void __launch_bounds__(256) k_H2s(const float* __restrict__ Wenc,
                                             const float* __restrict__ grids,
                                             const int* __restrict__ shx,
                                             const int* __restrict__ shy,
                                             float* __restrict__ ws) {
  __shared__ __align__(16) float sF[NF * NSAMP];  // [f][r], float4 per f
  __shared__ float sGr[NSAMP * 49];               // [r][g]
  __shared__ float sFeat[NF];
  __shared__ int   sSig[NSAMP];
  __shared__ float sRed[2][NSAMP][4];
  __shared__ float sRedH[4];
  __shared__ float sS[NSAMP];
  int t = threadIdx.x;
  int b = blockIdx.x;
  int i0s = b * NSAMP;
  for (int e = t; e < NSAMP * 49; e += 256) sGr[e] = grids[i0s * 49 + e];
  if (t < NSAMP) sSig[t] = shx[i0s + t] * 7 + shy[i0s + t];
  if (t < NF) sFeat[t] = ws[OFF_FEATS + t];
  __syncthreads();
  for (int idx = t; idx < NF * NSAMP; idx += 256) {
    int r = idx / NF, f = idx - r * NF;
    const float* T2 = ws + OFF_T + sSig[r] * (49 * NF) + f;
    const float* gr = sGr + r * 49;
    float acc = 0.f;
    #pragma unroll
    for (int g = 0; g < 49; ++g) acc = fmaf(T2[g * NF], gr[g], acc);
    sF[f * NSAMP + r] = acc;
  }
  __syncthreads();
  float accA[NSAMP], accB[NSAMP];
  #pragma unroll
  for (int r = 0; r < NSAMP; ++r) { accA[r] = 0.f; accB[r] = 0.f; }
  float h0 = 0.f, h1 = 0.f;
  // thread t owns d = 2t, 2t+1 -> one float2 load per f (halves load issues)
  const float2* W2 = (const float2*)Wenc;
  const float4* sF4 = (const float4*)sF;
  for (int f = 0; f < NF; ++f) {
    float2 w = W2[f * (ND / 2) + t];
    float fe = sFeat[f];
    h0 = fmaf(fe, w.x, h0);
    h1 = fmaf(fe, w.y, h1);
    float4 a4 = sF4[f];
    float a[NSAMP] = {a4.x, a4.y, a4.z, a4.w};
    #pragma unroll
    for (int r = 0; r < NSAMP; ++r) {
      accA[r] = fmaf(a[r], w.x, accA[r]);
      accB[r] = fmaf(a[r], w.y, accB[r]);
    }
  }
  int wave = t >> 6, lane = t & 63;
  float hq = h0 * h0 + h1 * h1;
  for (int off = 32; off; off >>= 1) hq += __shfl_down(hq, off);
  if (lane == 0) sRedH[wave] = hq;
  #pragma unroll
  for (int r = 0; r < NSAMP; ++r) {
    float np = accA[r] * h0 + accB[r] * h1;
    float sp = accA[r] * accA[r] + accB[r] * accB[r];
    for (int off = 32; off; off >>= 1) {
      np += __shfl_down(np, off);
      sp += __shfl_down(sp, off);
    }
    if (lane == 0) { sRed[0][r][wave] = np; sRed[1][r][wave] = sp; }
  }
  __syncthreads();
  if (t == 0) sRedH[0] = sqrtf(sRedH[0] + sRedH[1] + sRedH[2] + sRedH[3]);
  __syncthreads();
  if (t < NSAMP) {
    float np = sRed[0][t][0] + sRed[0][t][1] + sRed[0][t][2] + sRed[0][t][3];
    float sp = sRed[1][t][0] + sRed[1][t][1] + sRed[1][t][2] + sRed[1][t][3];
    float den = fmaxf(sRedH[0] * sqrtf(sp), 1e-8f);
    sS[t] = np / den;
  }
  __syncthreads();
  // flush this block's samples into G; k-fastest lanes -> coalesced runs
  for (int e = t; e < NSAMP * 3 * 49; e += 256) {
    int k = e % 49;
    int rp = e / 49;
    int r = rp / 3, p = rp - r * 3;
    float gv = sGr[r * 49 + k];
    if (gv != 0.f) {
      float s = sS[r];
      float add = (p == 0) ? 1.f : ((p == 1) ? s : s * s);
      atomicAdd(&ws[OFF_G + p * 2401 + sSig[r] * 49 + k], add);
    }
  }
}

// per-px-column C slice + final Welford output (one block per px)
__global__ void __launch_bounds__(256) k_CO(const float* __restrict__ ws,
                                            float* __restrict__ out) {
  __shared__ float Gl[3 * 2401];
  __shared__ float sC[NF];          // [k][sx][gy]
  int b = blockIdx.x;               // px
  int t = threadIdx.x;
  for (int e = t; e < 3 * 2401; e += 256) Gl[e] = ws[OFF_G + e];
  __syncthreads();
  const float4* WT = (const float4*)(ws + OFF_WT);
  if (t < NF) {
    int k = t / 49, r = t - k * 49;
    int sx = r / 7, gy = r % 7;
    float acc = 0.f;
    for (int sy = 0; sy < 7; ++sy) {
      float4 wt = WT[sy * 224 + b];
      int i0 = __float_as_int(wt.z), i1 = __float_as_int(wt.w);
      int base = k * 2401 + (sx * 7 + sy) * 49 + gy * 7;
      acc += wt.x * Gl[base + i0] + wt.y * Gl[base + i1];
    }
    sC[t] = acc;
  }
  __syncthreads();
  if (t < 224) {
    int py = t;
    float S0 = 0.f, S1 = 0.f, S2 = 0.f;
    for (int sx = 0; sx < 7; ++sx) {
      float4 wt = WT[sx * 224 + py];
      int i0 = __float_as_int(wt.z), i1 = __float_as_int(wt.w);
      int base = sx * 7;
      S0 += wt.x * sC[base + i0]      + wt.y * sC[base + i1];
      S1 += wt.x * sC[49 + base + i0] + wt.y * sC[49 + base + i1];
      S2 += wt.x * sC[98 + base + i0] + wt.y * sC[98 + base + i1];
    }
    float W = 1e-10f + S0;
    float R = S1 / W;
    float U = S2 - S1 * S1 / W;
    out[py * 224 + b] = R;
    out[224 * 224 + py * 224 + b] = U / (W - 1.0f);
  }
}

extern "C" void kernel_launch(void* const* d_in, const int* in_sizes, int n_in,
                              void* d_out, int out_size, void* d_ws, size_t ws_size,
                              hipStream_t stream) {
  const float* x     = (const float*)d_in[0];
  const float* Wenc  = (const float*)d_in[1];
  const float* grids = (const float*)d_in[2];
  const int*   shx   = (const int*)d_in[3];
  const int*   shy   = (const int*)d_in[4];
  float* out = (float*)d_out;
  float* ws  = (float*)d_ws;

  // 1029 work blocks + 1 WT block + 29 G-zero blocks
  k_VT<<<NBLK_VT + 1 + 29, 256, 0, stream>>>(x, ws);
  k_H2s<<<NHBLK, 256, 0, stream>>>(Wenc, grids, shx, shy, ws);
  k_CO<<<224, 256, 0, stream>>>(ws, out);
}